// Round 5
// baseline (1507.427 us; speedup 1.0000x reference)
//
#include <hip/hip_runtime.h>
#include <math.h>

#ifndef M_PI
#define M_PI 3.14159265358979323846
#endif

#define IN_HW 512
#define OUT_HW 1024
#define NB 32
#define NC 3
#define TOH 32
#define TOW 128
#define PATCH_H 24   // TOH/2 + 8
#define PATCH_W 72   // TOW/2 + 8
#define NTHREADS 256

// ---------------- sortable-key encoding for f32 atomics ----------------------
__device__ __forceinline__ unsigned enc_f(float f) {
  unsigned u = __float_as_uint(f);
  return (u & 0x80000000u) ? ~u : (u | 0x80000000u);
}
__device__ __forceinline__ float dec_f(unsigned k) {
  unsigned u = (k & 0x80000000u) ? (k ^ 0x80000000u) : ~k;
  return __uint_as_float(u);
}

// ---------------- Lanczos4 weights, 2x upsample: two phases ------------------
// even out-row o=2k: src = k-0.25, base=k-1, taps -> rows k-4+j, d = 3.75-j
// odd  out-row o=2k+1: src = k+0.25, base=k,  taps -> rows k-3+j, d = 3.25-j
// computed in f64 (sin/pi), normalized to sum 1, stored f32 (1-ulp accurate,
// which is plenty under the saturating-u8 output: worst case ±1 level).
__device__ void make_weights(float (*wn)[8] /* [0]=even,[1]=odd */) {
  if (threadIdx.x == 0) {
    for (int ph = 0; ph < 2; ++ph) {
      double w[8], s = 0.0;
      for (int j = 0; j < 8; ++j) {
        double d = fabs((ph ? 3.25 : 3.75) - (double)j);
        double y1 = M_PI * d, y2 = M_PI * (d * 0.25);
        w[j] = (sin(y1) / y1) * (sin(y2) / y2);
        s += w[j];
      }
      for (int j = 0; j < 8; ++j) wn[ph][j] = (float)(w[j] / s);
    }
  }
}

// ---------------- separable resize of one 32x128 output tile (f32, FMA) ------
__device__ __forceinline__ void compute_tile(
    const float* __restrict__ xchan, int oh0, int ow0, int tid,
    float (*patch)[PATCH_W], float (*vert)[PATCH_W], const float (*wn)[8],
    float px[16]) {
  const int row0 = (oh0 >> 1) - 4;
  const int col0 = (ow0 >> 1) - 4;
  for (int e = tid; e < PATCH_H * PATCH_W; e += NTHREADS) {
    int pr = e / PATCH_W, pc = e - pr * PATCH_W;
    int gr = row0 + pr; gr = gr < 0 ? 0 : (gr > IN_HW - 1 ? IN_HW - 1 : gr);
    int gc = col0 + pc; gc = gc < 0 ? 0 : (gc > IN_HW - 1 ? IN_HW - 1 : gc);
    patch[pr][pc] = xchan[gr * IN_HW + gc];
  }
  __syncthreads();
  // vertical: out rows r (local). r even=2q -> base q; r odd=2q+1 -> base q+1
  for (int e = tid; e < TOH * PATCH_W; e += NTHREADS) {
    int r = e / PATCH_W, c = e - r * PATCH_W;
    int q = (r >> 1) + (r & 1);
    const float* w = wn[r & 1];
    float acc = 0.f;
#pragma unroll
    for (int j = 0; j < 8; ++j) acc = fmaf(w[j], patch[q + j][c], acc);
    vert[r][c] = acc;
  }
  __syncthreads();
  // horizontal: thread -> col cw = tid&127, rows r = (tid>>7) + 2i
  const int cw = tid & (TOW - 1);
  const int rb = tid >> 7;
  const int pw = cw & 1;
  const int cb = (cw >> 1) + pw;       // local col base; max 64+7=71 < 72
  const float* w = wn[pw];
#pragma unroll
  for (int i = 0; i < 16; ++i) {
    int r = rb + 2 * i;
    float acc = 0.f;
#pragma unroll
    for (int j = 0; j < 8; ++j) acc = fmaf(w[j], vert[r][cb + j], acc);
    px[i] = acc;
  }
}

// ---------------- kernel 0: init min/max key slots (ws is poisoned) ----------
__global__ void k_init(unsigned* __restrict__ maxk, unsigned* __restrict__ mink) {
  int i = threadIdx.x;
  if (i < NB) maxk[i] = 0u;
  else if (i < 2 * NB) mink[i - NB] = 0xFFFFFFFFu;
}

// ---------------- kernel 1: resize + per-image min/max -----------------------
__global__ __launch_bounds__(NTHREADS) void k_minmax(
    const float* __restrict__ x,
    unsigned* __restrict__ maxk, unsigned* __restrict__ mink) {
  __shared__ float patch[PATCH_H][PATCH_W];
  __shared__ float vert[TOH][PATCH_W];
  __shared__ float wn[2][8];
  __shared__ float red[NTHREADS];
  const int tid = threadIdx.x;
  make_weights(wn);
  __syncthreads();

  const int bc = blockIdx.z;
  const float* xchan = x + (size_t)bc * (IN_HW * IN_HW);
  float px[16];
  compute_tile(xchan, blockIdx.y * TOH, blockIdx.x * TOW, tid, patch, vert, wn, px);

  float mn = px[0], mx = px[0];
#pragma unroll
  for (int i = 1; i < 16; ++i) { mn = fminf(mn, px[i]); mx = fmaxf(mx, px[i]); }

  red[tid] = mx; __syncthreads();
  for (int s = NTHREADS / 2; s > 0; s >>= 1) {
    if (tid < s) red[tid] = fmaxf(red[tid], red[tid + s]);
    __syncthreads();
  }
  float bmx = red[0]; __syncthreads();
  red[tid] = mn; __syncthreads();
  for (int s = NTHREADS / 2; s > 0; s >>= 1) {
    if (tid < s) red[tid] = fminf(red[tid], red[tid + s]);
    __syncthreads();
  }
  if (tid == 0) {
    int b = bc / NC;
    atomicMax(&maxk[b], enc_f(bmx));
    atomicMin(&mink[b], enc_f(red[0]));
  }
}

// ---------------- kernel 2: resize + renorm + SATURATING u8 store (int32) ----
__global__ __launch_bounds__(NTHREADS) void k_final(
    const float* __restrict__ x,
    const unsigned* __restrict__ maxk, const unsigned* __restrict__ mink,
    int* __restrict__ out) {
  __shared__ float patch[PATCH_H][PATCH_W];
  __shared__ float vert[TOH][PATCH_W];
  __shared__ float wn[2][8];
  const int tid = threadIdx.x;
  make_weights(wn);
  __syncthreads();

  const int bc = blockIdx.z;
  const int b = bc / NC;
  const float mx = dec_f(maxk[b]);
  const float mn = dec_f(mink[b]);
  const bool applies = (mx - mn) > 1.0f;
  const float ott = 1.0f / 255.0f;
  const float ubt = -10.0f / 255.0f;
  const float otr = mx - 1.0f;
  const float cA = ott / ((otr != 0.0f) ? otr : 1.0f);
  const float cB = ubt / ((mn != 0.0f) ? mn : 1.0f);
  const float om_ott = 1.0f - ott;
  const float om_ubt = 1.0f - ubt;

  const float* xchan = x + (size_t)bc * (IN_HW * IN_HW);
  const int oh0 = blockIdx.y * TOH, ow0 = blockIdx.x * TOW;
  float px[16];
  compute_tile(xchan, oh0, ow0, tid, patch, vert, wn, px);

  const int cw = tid & (TOW - 1);
  const int rb = tid >> 7;
  const size_t outbase = (size_t)bc * OUT_HW * OUT_HW;
#pragma unroll
  for (int i = 0; i < 16; ++i) {
    int oh = oh0 + rb + 2 * i, ow = ow0 + cw;
    float img = px[i];
    float v1 = (img > 1.0f) ? fmaf(img - 1.0f, cA, om_ott)
             : (img < 1.0f) ? img * om_ott : img;
    float v2 = (v1 < 0.0f) ? fmaf(v1, cB, ubt)
             : (v1 > 0.0f) ? v1 * om_ubt : v1;
    float y = (applies ? v2 : img) * 255.0f;
    // XLA/jax f32->u8 convert: round toward zero, SATURATE to [0,255]
    int t = (int)y;
    t = t < 0 ? 0 : (t > 255 ? 255 : t);
    out[outbase + (size_t)oh * OUT_HW + ow] = t;
  }
}

extern "C" void kernel_launch(void* const* d_in, const int* in_sizes, int n_in,
                              void* d_out, int out_size, void* d_ws, size_t ws_size,
                              hipStream_t stream) {
  const float* x = (const float*)d_in[0];
  int* out = (int*)d_out;
  unsigned* maxk = (unsigned*)d_ws;
  unsigned* mink = maxk + NB;

  hipLaunchKernelGGL(k_init, dim3(1), dim3(64), 0, stream, maxk, mink);
  dim3 grid(OUT_HW / TOW, OUT_HW / TOH, NB * NC);
  hipLaunchKernelGGL(k_minmax, grid, dim3(NTHREADS), 0, stream, x, maxk, mink);
  hipLaunchKernelGGL(k_final, grid, dim3(NTHREADS), 0, stream, x, maxk, mink, out);
}